// Round 11
// baseline (164.913 us; speedup 1.0000x reference)
//
#include <hip/hip_runtime.h>
#include <hip/hip_bf16.h>

#define B_SEG  8192
#define DEG    32
#define D_DIM  256
#define TWO_D  512
#define ACTD   512
#define SLOPE  0.2f

typedef __attribute__((ext_vector_type(8))) short bf16x8;   // 8 bf16 (4 VGPRs)
typedef __attribute__((ext_vector_type(4))) float f32x4;

// ---------------- workspace layout (bytes) ----------------
#define OFF_VNOW  ((size_t)0)
#define OFF_VNB   ((size_t)1024)
#define OFF_CNST  ((size_t)2048)
#define OFF_W1T   ((size_t)4096)                               // 512x768 bf16
#define OFF_W2T   (OFF_W1T + (size_t)768*512*2)                // 1024x512 bf16
#define OFF_W3T   (OFF_W2T + (size_t)512*1024*2)               // 512x1024 bf16
#define OFF_X1    (OFF_W3T + (size_t)1024*512*2)               // 8192x768 bf16
#define OFF_X2    (OFF_X1 + (size_t)B_SEG*768*2)               // 8192x512 bf16
#define OFF_X3    (OFF_X2 + (size_t)B_SEG*512*2)               // 8192x1024 bf16
#define OFF_LOG   (OFF_X3 + (size_t)B_SEG*1024*2)              // 8192x512 f32

// ---------------- direct global->LDS (16B/lane) ----------------
typedef const unsigned int __attribute__((address_space(1)))* gas_ptr;
typedef unsigned int __attribute__((address_space(3)))* las_ptr;

__device__ __forceinline__ void gload_lds16(const void* g, void* l) {
    __builtin_amdgcn_global_load_lds((gas_ptr)g, (las_ptr)l, 16, 0, 0);
}

// ---------------- merged prep: vectors (block 0, coalesced; passed r8/r9) + 3 transposes ----------------
__global__ __launch_bounds__(256) void prep_all(
        const float* __restrict__ attn_w, const float* __restrict__ attn_b,
        const float* __restrict__ aw_w, const float* __restrict__ aw_b,
        const float* __restrict__ w1, const float* __restrict__ w2, const float* __restrict__ w3,
        float* __restrict__ vnow, float* __restrict__ vnb, float* __restrict__ cnst,
        __hip_bfloat16* __restrict__ w1T, __hip_bfloat16* __restrict__ w2T,
        __hip_bfloat16* __restrict__ w3T) {
    int bid = blockIdx.x;
    if (bid == 0) {
        const int lane = threadIdx.x & 63;
        const int w    = threadIdx.x >> 6;
        const float2 a0 = *(const float2*)&aw_w[lane * 2];
        const float2 a1 = *(const float2*)&aw_w[128 + lane * 2];
#pragma unroll 2
        for (int i = 0; i < 64; ++i) {
            const int d = w * 64 + i;
            const float2 wr = *(const float2*)&attn_w[d * 128 + lane * 2];
            float s0 = wr.x * a0.x + wr.y * a0.y;
            float s1 = wr.x * a1.x + wr.y * a1.y;
#pragma unroll
            for (int off = 32; off; off >>= 1) {
                s0 += __shfl_xor(s0, off);
                s1 += __shfl_xor(s1, off);
            }
            if (lane == 0) { vnow[d] = s0; vnb[d] = s1; }
        }
        if (w == 0) {
            const float2 ab = *(const float2*)&attn_b[lane * 2];
            float c = ab.x * (a0.x + a1.x) + ab.y * (a0.y + a1.y);
#pragma unroll
            for (int off = 32; off; off >>= 1) c += __shfl_xor(c, off);
            if (lane == 0) cnst[0] = c + aw_b[0];
        }
        return;
    }
    bid -= 1;
    const float* src;
    __hip_bfloat16* dst;
    int K, N;
    if (bid < 384)      { src = w1; dst = w1T; K = 768;  N = 512;  }
    else if (bid < 896) { bid -= 384; src = w2; dst = w2T; K = 512;  N = 1024; }
    else                { bid -= 896; src = w3; dst = w3T; K = 1024; N = 512;  }
    const int tk = K >> 5;
    const int bk = (bid % tk) * 32;
    const int bn = (bid / tk) * 32;

    __shared__ float tile[32][33];
    const int tx = threadIdx.x & 31;
    const int ty = threadIdx.x >> 5;   // 0..7
#pragma unroll
    for (int i = 0; i < 32; i += 8)
        tile[ty + i][tx] = src[(size_t)(bk + ty + i) * N + (bn + tx)];
    __syncthreads();
#pragma unroll
    for (int i = 0; i < 32; i += 8)
        dst[(size_t)(bn + ty + i) * K + (bk + tx)] = __float2bfloat16(tile[tx][ty + i]);
}

// ---------------- fused attention (round-2 verified, untouched) ----------------
__global__ __launch_bounds__(256) void attn_fused(
        const float* __restrict__ state, const float* __restrict__ now_emb,
        const float* __restrict__ neigh, const float* __restrict__ vnow,
        const float* __restrict__ vnb, const float* __restrict__ cnst,
        __hip_bfloat16* __restrict__ X1) {
    const int b    = blockIdx.x;
    const int tid  = threadIdx.x;
    const int lane = tid & 63;
    const int w    = tid >> 6;     // wave 0..3
    const int l4   = lane * 4;

    __shared__ float s_score[DEG];
    __shared__ float s_now;
    __shared__ float s_part[4][D_DIM];   // 4 KB

    const float4 vb = *(const float4*)&vnb[l4];
    float4 nv[8];
#pragma unroll
    for (int i = 0; i < 8; ++i) {
        const int e = w * 8 + i;
        nv[i] = *(const float4*)&neigh[((size_t)b * DEG + e) * D_DIM + l4];
        float p = nv[i].x * vb.x + nv[i].y * vb.y + nv[i].z * vb.z + nv[i].w * vb.w;
#pragma unroll
        for (int off = 32; off; off >>= 1) p += __shfl_xor(p, off);
        if (lane == 0) s_score[e] = p;
    }
    if (w == 0) {
        const float4 va = *(const float4*)&vnow[l4];
        const float4 ne = *(const float4*)&now_emb[(size_t)b * D_DIM + l4];
        float p = ne.x * va.x + ne.y * va.y + ne.z * va.z + ne.w * va.w;
#pragma unroll
        for (int off = 32; off; off >>= 1) p += __shfl_xor(p, off);
        if (lane == 0) s_now = p + cnst[0];
    }
    __syncthreads();

    if (w == 0) {
        float s = (lane < DEG) ? (s_score[lane] + s_now) : -3.4e38f;
        s = (s >= 0.f) ? s : SLOPE * s;
        float m = s;
#pragma unroll
        for (int off = 32; off; off >>= 1) m = fmaxf(m, __shfl_xor(m, off));
        const float e = (lane < DEG) ? expf(s - m) : 0.f;
        float t = e;
#pragma unroll
        for (int off = 32; off; off >>= 1) t += __shfl_xor(t, off);
        if (lane < DEG) s_score[lane] = e / t;          // alpha
    }
    __syncthreads();

    float4 part = {0.f, 0.f, 0.f, 0.f};
#pragma unroll
    for (int i = 0; i < 8; ++i) {
        const float al = s_score[w * 8 + i];
        part.x = fmaf(al, nv[i].x, part.x);
        part.y = fmaf(al, nv[i].y, part.y);
        part.z = fmaf(al, nv[i].z, part.z);
        part.w = fmaf(al, nv[i].w, part.w);
    }
    *(float4*)&s_part[w][l4] = part;
    __syncthreads();

    const float a = s_part[0][tid] + s_part[1][tid] + s_part[2][tid] + s_part[3][tid];

    __hip_bfloat16* xrow = X1 + (size_t)b * 768;
    xrow[512 + tid] = __float2bfloat16(a);
    const float2 st = *(const float2*)&state[(size_t)b * TWO_D + 2 * tid];
    __hip_bfloat162 h;
    h.x = __float2bfloat16(st.x);
    h.y = __float2bfloat16(st.y);
    *(__hip_bfloat162*)&xrow[2 * tid] = h;
}

// ---------------- bf16 MFMA GEMM v3c: 64x128, BK=64, dbuf, swizzled LDS,
// SINGLE barrier per chunk with STAGE placed AFTER the barrier (race-free):
//   for t: vmcnt(0) -> s_barrier -> STAGE(t+1, cur^1) -> compute(buf[cur])
// (a) iter t-1's reads of buf[cur^1] complete before each wave reaches the iter-t
//     barrier (MFMA lgkmcnt waits); STAGE into buf[cur^1] is issued only after it.
// (b) tile t's LDS writes drained by each wave's own vmcnt(0) before the barrier.
// (c) fast wave's next STAGE is blocked by the next barrier until all reads finish.
template <int RELU, int OUTF32, int LN_N>
__global__ __launch_bounds__(256) void gemm_db(
        const __hip_bfloat16* __restrict__ A, const __hip_bfloat16* __restrict__ BT,
        const float* __restrict__ bias, void* __restrict__ Cout, int N, int K) {
    __shared__ __hip_bfloat16 sA[2][64 * 64];    // 8 KB per buf
    __shared__ __hip_bfloat16 sB[2][128 * 64];   // 16 KB per buf  (48 KB total)

    const int tid  = threadIdx.x;
    const int lane = tid & 63;
    const int wv   = tid >> 6;
    const int wr   = wv >> 1;
    const int wc   = wv & 1;

    // XCD swizzle (m157; nwg % 8 == 0 for all three launches)
    const int cpx = (int)gridDim.x >> 3;
    const int swz = ((int)blockIdx.x & 7) * cpx + ((int)blockIdx.x >> 3);
    const size_t mBase = (size_t)(swz >> LN_N) * 64;
    const size_t nBase = (size_t)(swz & ((1 << LN_N) - 1)) * 128;
    const size_t Kb = (size_t)K * 2;

    f32x4 acc[2][4];
#pragma unroll
    for (int r = 0; r < 2; ++r)
#pragma unroll
        for (int c = 0; c < 4; ++c) acc[r][c] = (f32x4){0.f, 0.f, 0.f, 0.f};

    const int srow  = tid >> 3;                          // 0..31
    const int kbLog = ((tid & 7) ^ (srow & 7)) << 4;     // pre-swizzled source k-byte (rule 21)
    const char* gA = (const char*)A  + (mBase + srow) * Kb + kbLog;
    const char* gB = (const char*)BT + (nBase + srow) * Kb + kbLog;
    char* lA = (char*)&sA[0][0] + tid * 16;
    char* lB = (char*)&sB[0][0] + tid * 16;

    const int fr  = lane & 15;
    const int fkb = (lane >> 4) * 16;
    const char* sAb = (const char*)&sA[0][0];
    const char* sBb = (const char*)&sB[0][0];

    const int nk = K >> 6;

#define STAGE(T, BUF) do {                                                         \
        const size_t kOff = (size_t)(T) * 128;                                     \
        gload_lds16(gA + kOff,           lA + (BUF) * 8192);                       \
        gload_lds16(gA + kOff + 32 * Kb, lA + (BUF) * 8192 + 4096);                \
        gload_lds16(gB + kOff,           lB + (BUF) * 16384);                      \
        gload_lds16(gB + kOff + 32 * Kb, lB + (BUF) * 16384 + 4096);               \
        gload_lds16(gB + kOff + 64 * Kb, lB + (BUF) * 16384 + 8192);               \
        gload_lds16(gB + kOff + 96 * Kb, lB + (BUF) * 16384 + 12288);              \
    } while (0)

#define SWZ(ROW, KB) ((ROW) * 128 + ((KB) ^ (((ROW) & 7) << 4)))

    STAGE(0, 0);

    int cur = 0;
    for (int t = 0; t < nk; ++t) {
        asm volatile("s_waitcnt vmcnt(0)" ::: "memory");  // drain tile t's 6 loads (only
                                                          // ones outstanding; had a full
                                                          // compute phase to land)
        __builtin_amdgcn_s_barrier();        // tile t visible; iter t-1 reads sealed
        __builtin_amdgcn_sched_barrier(0);   // nothing hoists above the barrier

        if (t + 1 < nk) STAGE(t + 1, cur ^ 1);   // safe: buf[cur^1] readers sealed above

        const char* bufA = sAb + cur * 8192;
        const char* bufB = sBb + cur * 16384;
#pragma unroll
        for (int ks = 0; ks < 2; ++ks) {
            bf16x8 aF[2], bF[4];
#pragma unroll
            for (int r = 0; r < 2; ++r) {
                const int row = wr * 32 + r * 16 + fr;
                aF[r] = *(const bf16x8*)(bufA + SWZ(row, ks * 64 + fkb));
            }
#pragma unroll
            for (int c = 0; c < 4; ++c) {
                const int row = wc * 64 + c * 16 + fr;
                bF[c] = *(const bf16x8*)(bufB + SWZ(row, ks * 64 + fkb));
            }
#pragma unroll
            for (int r = 0; r < 2; ++r)
#pragma unroll
                for (int c = 0; c < 4; ++c)
                    acc[r][c] = __builtin_amdgcn_mfma_f32_16x16x32_bf16(aF[r], bF[c], acc[r][c], 0, 0, 0);
        }
        __builtin_amdgcn_sched_barrier(0);   // reads/MFMA stay in this iteration
        cur ^= 1;
    }
#undef STAGE
#undef SWZ

    // epilogue: C/D layout col = lane&15, row = (lane>>4)*4 + q  [m89-verified]
    const int fq = lane >> 4;
#pragma unroll
    for (int r = 0; r < 2; ++r) {
#pragma unroll
        for (int c = 0; c < 4; ++c) {
            const size_t col = nBase + wc * 64 + c * 16 + fr;
            const float bcol = bias[col];
#pragma unroll
            for (int q = 0; q < 4; ++q) {
                const size_t row = mBase + wr * 32 + r * 16 + fq * 4 + q;
                float v = acc[r][c][q] + bcol;
                if (RELU) v = fmaxf(v, 0.f);
                if (OUTF32) ((float*)Cout)[row * N + col] = v;
                else ((__hip_bfloat16*)Cout)[row * N + col] = __float2bfloat16(v);
            }
        }
    }
}

// ---------------- final row softmax over 512 (float2-vectorized) ----------------
__global__ __launch_bounds__(256) void softmax512(const float* __restrict__ logits,
                                                  float* __restrict__ out) {
    const int b    = blockIdx.x;
    const int tid  = threadIdx.x;
    const int lane = tid & 63;
    const int w    = tid >> 6;
    const float2* row2 = (const float2*)(logits + (size_t)b * ACTD);
    const float2 x = row2[tid];
    float m = fmaxf(x.x, x.y);
#pragma unroll
    for (int off = 32; off; off >>= 1) m = fmaxf(m, __shfl_xor(m, off));
    __shared__ float sm[4], ss[4];
    if (lane == 0) sm[w] = m;
    __syncthreads();
    m = fmaxf(fmaxf(sm[0], sm[1]), fmaxf(sm[2], sm[3]));
    const float e0 = expf(x.x - m), e1 = expf(x.y - m);
    float t = e0 + e1;
#pragma unroll
    for (int off = 32; off; off >>= 1) t += __shfl_xor(t, off);
    if (lane == 0) ss[w] = t;
    __syncthreads();
    const float inv = 1.f / (ss[0] + ss[1] + ss[2] + ss[3]);
    float2 o; o.x = e0 * inv; o.y = e1 * inv;
    ((float2*)(out + (size_t)b * ACTD))[tid] = o;
}

// ---------------- launch ----------------
extern "C" void kernel_launch(void* const* d_in, const int* in_sizes, int n_in,
                              void* d_out, int out_size, void* d_ws, size_t ws_size,
                              hipStream_t stream) {
    const float* state   = (const float*)d_in[0];
    const float* now_emb = (const float*)d_in[1];
    const float* neigh   = (const float*)d_in[2];
    // d_in[3] = seg_ids: fixed repeat(arange(B), DEG) -> segment b owns rows 32b..32b+31
    const float* attn_w  = (const float*)d_in[4];
    const float* attn_b  = (const float*)d_in[5];
    const float* aw_w    = (const float*)d_in[6];
    const float* aw_b    = (const float*)d_in[7];
    const float* w1      = (const float*)d_in[8];
    const float* b1      = (const float*)d_in[9];
    const float* w2      = (const float*)d_in[10];
    const float* b2      = (const float*)d_in[11];
    const float* w3      = (const float*)d_in[12];
    const float* b3      = (const float*)d_in[13];
    float* out = (float*)d_out;

    char* ws = (char*)d_ws;
    float*          vnow = (float*)(ws + OFF_VNOW);
    float*          vnb  = (float*)(ws + OFF_VNB);
    float*          cnst = (float*)(ws + OFF_CNST);
    __hip_bfloat16* w1T  = (__hip_bfloat16*)(ws + OFF_W1T);
    __hip_bfloat16* w2T  = (__hip_bfloat16*)(ws + OFF_W2T);
    __hip_bfloat16* w3T  = (__hip_bfloat16*)(ws + OFF_W3T);
    __hip_bfloat16* X1   = (__hip_bfloat16*)(ws + OFF_X1);
    __hip_bfloat16* X2   = (__hip_bfloat16*)(ws + OFF_X2);
    __hip_bfloat16* X3   = (__hip_bfloat16*)(ws + OFF_X3);
    float*          lgts = (float*)(ws + OFF_LOG);

    prep_all<<<1409, 256, 0, stream>>>(attn_w, attn_b, aw_w, aw_b, w1, w2, w3,
                                       vnow, vnb, cnst, w1T, w2T, w3T);
    attn_fused<<<B_SEG, 256, 0, stream>>>(state, now_emb, neigh, vnow, vnb, cnst, X1);
    gemm_db<1, 0, 2><<<512,  256, 0, stream>>>(X1, w1T, b1, (void*)X2, 512, 768);
    gemm_db<1, 0, 3><<<1024, 256, 0, stream>>>(X2, w2T, b2, (void*)X3, 1024, 512);
    gemm_db<0, 1, 2><<<512,  256, 0, stream>>>(X3, w3T, b3, (void*)lgts, 512, 1024);
    softmax512<<<B_SEG, 256, 0, stream>>>(lgts, out);
}

// Round 12
// 163.353 us; speedup vs baseline: 1.0095x; 1.0095x over previous
//
#include <hip/hip_runtime.h>
#include <hip/hip_bf16.h>

#define B_SEG  8192
#define DEG    32
#define D_DIM  256
#define TWO_D  512
#define ACTD   512
#define SLOPE  0.2f

typedef __attribute__((ext_vector_type(8))) short bf16x8;   // 8 bf16 (4 VGPRs)
typedef __attribute__((ext_vector_type(4))) float f32x4;

// ---------------- workspace layout (bytes) ----------------
#define OFF_VNOW  ((size_t)0)
#define OFF_VNB   ((size_t)1024)
#define OFF_CNST  ((size_t)2048)
#define OFF_W1T   ((size_t)4096)                               // 512x768 bf16
#define OFF_W2T   (OFF_W1T + (size_t)768*512*2)                // 1024x512 bf16
#define OFF_W3T   (OFF_W2T + (size_t)512*1024*2)               // 512x1024 bf16
#define OFF_X1    (OFF_W3T + (size_t)1024*512*2)               // 8192x768 bf16
#define OFF_X2    (OFF_X1 + (size_t)B_SEG*768*2)               // 8192x512 bf16
#define OFF_X3    (OFF_X2 + (size_t)B_SEG*512*2)               // 8192x1024 bf16
#define OFF_LOG   (OFF_X3 + (size_t)B_SEG*1024*2)              // 8192x512 f32

// ---------------- direct global->LDS (16B/lane) ----------------
typedef const unsigned int __attribute__((address_space(1)))* gas_ptr;
typedef unsigned int __attribute__((address_space(3)))* las_ptr;

__device__ __forceinline__ void gload_lds16(const void* g, void* l) {
    __builtin_amdgcn_global_load_lds((gas_ptr)g, (las_ptr)l, 16, 0, 0);
}

// ---------------- merged prep: vectors (block 0, coalesced; passed r8/r9/r11) + 3 transposes ----------------
__global__ __launch_bounds__(256) void prep_all(
        const float* __restrict__ attn_w, const float* __restrict__ attn_b,
        const float* __restrict__ aw_w, const float* __restrict__ aw_b,
        const float* __restrict__ w1, const float* __restrict__ w2, const float* __restrict__ w3,
        float* __restrict__ vnow, float* __restrict__ vnb, float* __restrict__ cnst,
        __hip_bfloat16* __restrict__ w1T, __hip_bfloat16* __restrict__ w2T,
        __hip_bfloat16* __restrict__ w3T) {
    int bid = blockIdx.x;
    if (bid == 0) {
        const int lane = threadIdx.x & 63;
        const int w    = threadIdx.x >> 6;
        const float2 a0 = *(const float2*)&aw_w[lane * 2];
        const float2 a1 = *(const float2*)&aw_w[128 + lane * 2];
#pragma unroll 2
        for (int i = 0; i < 64; ++i) {
            const int d = w * 64 + i;
            const float2 wr = *(const float2*)&attn_w[d * 128 + lane * 2];
            float s0 = wr.x * a0.x + wr.y * a0.y;
            float s1 = wr.x * a1.x + wr.y * a1.y;
#pragma unroll
            for (int off = 32; off; off >>= 1) {
                s0 += __shfl_xor(s0, off);
                s1 += __shfl_xor(s1, off);
            }
            if (lane == 0) { vnow[d] = s0; vnb[d] = s1; }
        }
        if (w == 0) {
            const float2 ab = *(const float2*)&attn_b[lane * 2];
            float c = ab.x * (a0.x + a1.x) + ab.y * (a0.y + a1.y);
#pragma unroll
            for (int off = 32; off; off >>= 1) c += __shfl_xor(c, off);
            if (lane == 0) cnst[0] = c + aw_b[0];
        }
        return;
    }
    bid -= 1;
    const float* src;
    __hip_bfloat16* dst;
    int K, N;
    if (bid < 384)      { src = w1; dst = w1T; K = 768;  N = 512;  }
    else if (bid < 896) { bid -= 384; src = w2; dst = w2T; K = 512;  N = 1024; }
    else                { bid -= 896; src = w3; dst = w3T; K = 1024; N = 512;  }
    const int tk = K >> 5;
    const int bk = (bid % tk) * 32;
    const int bn = (bid / tk) * 32;

    __shared__ float tile[32][33];
    const int tx = threadIdx.x & 31;
    const int ty = threadIdx.x >> 5;   // 0..7
#pragma unroll
    for (int i = 0; i < 32; i += 8)
        tile[ty + i][tx] = src[(size_t)(bk + ty + i) * N + (bn + tx)];
    __syncthreads();
#pragma unroll
    for (int i = 0; i < 32; i += 8)
        dst[(size_t)(bn + ty + i) * K + (bk + tx)] = __float2bfloat16(tile[tx][ty + i]);
}

// ---------------- fused attention (round-2 verified, untouched) ----------------
__global__ __launch_bounds__(256) void attn_fused(
        const float* __restrict__ state, const float* __restrict__ now_emb,
        const float* __restrict__ neigh, const float* __restrict__ vnow,
        const float* __restrict__ vnb, const float* __restrict__ cnst,
        __hip_bfloat16* __restrict__ X1) {
    const int b    = blockIdx.x;
    const int tid  = threadIdx.x;
    const int lane = tid & 63;
    const int w    = tid >> 6;     // wave 0..3
    const int l4   = lane * 4;

    __shared__ float s_score[DEG];
    __shared__ float s_now;
    __shared__ float s_part[4][D_DIM];   // 4 KB

    const float4 vb = *(const float4*)&vnb[l4];
    float4 nv[8];
#pragma unroll
    for (int i = 0; i < 8; ++i) {
        const int e = w * 8 + i;
        nv[i] = *(const float4*)&neigh[((size_t)b * DEG + e) * D_DIM + l4];
        float p = nv[i].x * vb.x + nv[i].y * vb.y + nv[i].z * vb.z + nv[i].w * vb.w;
#pragma unroll
        for (int off = 32; off; off >>= 1) p += __shfl_xor(p, off);
        if (lane == 0) s_score[e] = p;
    }
    if (w == 0) {
        const float4 va = *(const float4*)&vnow[l4];
        const float4 ne = *(const float4*)&now_emb[(size_t)b * D_DIM + l4];
        float p = ne.x * va.x + ne.y * va.y + ne.z * va.z + ne.w * va.w;
#pragma unroll
        for (int off = 32; off; off >>= 1) p += __shfl_xor(p, off);
        if (lane == 0) s_now = p + cnst[0];
    }
    __syncthreads();

    if (w == 0) {
        float s = (lane < DEG) ? (s_score[lane] + s_now) : -3.4e38f;
        s = (s >= 0.f) ? s : SLOPE * s;
        float m = s;
#pragma unroll
        for (int off = 32; off; off >>= 1) m = fmaxf(m, __shfl_xor(m, off));
        const float e = (lane < DEG) ? expf(s - m) : 0.f;
        float t = e;
#pragma unroll
        for (int off = 32; off; off >>= 1) t += __shfl_xor(t, off);
        if (lane < DEG) s_score[lane] = e / t;          // alpha
    }
    __syncthreads();

    float4 part = {0.f, 0.f, 0.f, 0.f};
#pragma unroll
    for (int i = 0; i < 8; ++i) {
        const float al = s_score[w * 8 + i];
        part.x = fmaf(al, nv[i].x, part.x);
        part.y = fmaf(al, nv[i].y, part.y);
        part.z = fmaf(al, nv[i].z, part.z);
        part.w = fmaf(al, nv[i].w, part.w);
    }
    *(float4*)&s_part[w][l4] = part;
    __syncthreads();

    const float a = s_part[0][tid] + s_part[1][tid] + s_part[2][tid] + s_part[3][tid];

    __hip_bfloat16* xrow = X1 + (size_t)b * 768;
    xrow[512 + tid] = __float2bfloat16(a);
    const float2 st = *(const float2*)&state[(size_t)b * TWO_D + 2 * tid];
    __hip_bfloat162 h;
    h.x = __float2bfloat16(st.x);
    h.y = __float2bfloat16(st.y);
    *(__hip_bfloat162*)&xrow[2 * tid] = h;
}

// ---------------- bf16 MFMA GEMM v3 (round-6 exact, best-known 133.6 µs config):
// 64x128, BK=64, counted-vmcnt 2-buffer, swizzled LDS, two barriers per chunk.
// STAGE(t+1) issued BEFORE s_waitcnt vmcnt(6) -> next tile's loads stay in flight
// across the barrier; only tile t's 6 loads drain. Never vmcnt(0) in the main loop.
template <int RELU, int OUTF32, int LN_N>
__global__ __launch_bounds__(256) void gemm_db(
        const __hip_bfloat16* __restrict__ A, const __hip_bfloat16* __restrict__ BT,
        const float* __restrict__ bias, void* __restrict__ Cout, int N, int K) {
    __shared__ __hip_bfloat16 sA[2][64 * 64];    // 8 KB per buf
    __shared__ __hip_bfloat16 sB[2][128 * 64];   // 16 KB per buf  (48 KB total)

    const int tid  = threadIdx.x;
    const int lane = tid & 63;
    const int wv   = tid >> 6;
    const int wr   = wv >> 1;
    const int wc   = wv & 1;

    // XCD swizzle (m157; nwg % 8 == 0 for all three launches)
    const int cpx = (int)gridDim.x >> 3;
    const int swz = ((int)blockIdx.x & 7) * cpx + ((int)blockIdx.x >> 3);
    const size_t mBase = (size_t)(swz >> LN_N) * 64;
    const size_t nBase = (size_t)(swz & ((1 << LN_N) - 1)) * 128;
    const size_t Kb = (size_t)K * 2;

    f32x4 acc[2][4];
#pragma unroll
    for (int r = 0; r < 2; ++r)
#pragma unroll
        for (int c = 0; c < 4; ++c) acc[r][c] = (f32x4){0.f, 0.f, 0.f, 0.f};

    const int srow  = tid >> 3;                          // 0..31
    const int kbLog = ((tid & 7) ^ (srow & 7)) << 4;     // pre-swizzled source k-byte (rule 21)
    const char* gA = (const char*)A  + (mBase + srow) * Kb + kbLog;
    const char* gB = (const char*)BT + (nBase + srow) * Kb + kbLog;
    char* lA = (char*)&sA[0][0] + tid * 16;
    char* lB = (char*)&sB[0][0] + tid * 16;

    const int fr  = lane & 15;
    const int fkb = (lane >> 4) * 16;
    const char* sAb = (const char*)&sA[0][0];
    const char* sBb = (const char*)&sB[0][0];

    const int nk = K >> 6;

#define STAGE(T, BUF) do {                                                         \
        const size_t kOff = (size_t)(T) * 128;                                     \
        gload_lds16(gA + kOff,           lA + (BUF) * 8192);                       \
        gload_lds16(gA + kOff + 32 * Kb, lA + (BUF) * 8192 + 4096);                \
        gload_lds16(gB + kOff,           lB + (BUF) * 16384);                      \
        gload_lds16(gB + kOff + 32 * Kb, lB + (BUF) * 16384 + 4096);               \
        gload_lds16(gB + kOff + 64 * Kb, lB + (BUF) * 16384 + 8192);               \
        gload_lds16(gB + kOff + 96 * Kb, lB + (BUF) * 16384 + 12288);              \
    } while (0)

#define SWZ(ROW, KB) ((ROW) * 128 + ((KB) ^ (((ROW) & 7) << 4)))

    STAGE(0, 0);

    int cur = 0;
    for (int t = 0; t < nk; ++t) {
        if (t + 1 < nk) {
            STAGE(t + 1, cur ^ 1);                          // issue next tile's 6 loads
            asm volatile("s_waitcnt vmcnt(6)" ::: "memory"); // drain only tile t's loads
        } else {
            asm volatile("s_waitcnt vmcnt(0)" ::: "memory"); // last tile: full drain
        }
        __builtin_amdgcn_s_barrier();        // tile t staged + visible to all waves
        __builtin_amdgcn_sched_barrier(0);   // no ds_read hoists above the barrier

        const char* bufA = sAb + cur * 8192;
        const char* bufB = sBb + cur * 16384;
#pragma unroll
        for (int ks = 0; ks < 2; ++ks) {
            bf16x8 aF[2], bF[4];
#pragma unroll
            for (int r = 0; r < 2; ++r) {
                const int row = wr * 32 + r * 16 + fr;
                aF[r] = *(const bf16x8*)(bufA + SWZ(row, ks * 64 + fkb));
            }
#pragma unroll
            for (int c = 0; c < 4; ++c) {
                const int row = wc * 64 + c * 16 + fr;
                bF[c] = *(const bf16x8*)(bufB + SWZ(row, ks * 64 + fkb));
            }
#pragma unroll
            for (int r = 0; r < 2; ++r)
#pragma unroll
                for (int c = 0; c < 4; ++c)
                    acc[r][c] = __builtin_amdgcn_mfma_f32_16x16x32_bf16(aF[r], bF[c], acc[r][c], 0, 0, 0);
        }
        __builtin_amdgcn_sched_barrier(0);   // no read sinks below the barrier
        __builtin_amdgcn_s_barrier();        // all waves done reading buf[cur]
        cur ^= 1;
    }
#undef STAGE
#undef SWZ

    // epilogue: C/D layout col = lane&15, row = (lane>>4)*4 + q  [m89-verified]
    const int fq = lane >> 4;
#pragma unroll
    for (int r = 0; r < 2; ++r) {
#pragma unroll
        for (int c = 0; c < 4; ++c) {
            const size_t col = nBase + wc * 64 + c * 16 + fr;
            const float bcol = bias[col];
#pragma unroll
            for (int q = 0; q < 4; ++q) {
                const size_t row = mBase + wr * 32 + r * 16 + fq * 4 + q;
                float v = acc[r][c][q] + bcol;
                if (RELU) v = fmaxf(v, 0.f);
                if (OUTF32) ((float*)Cout)[row * N + col] = v;
                else ((__hip_bfloat16*)Cout)[row * N + col] = __float2bfloat16(v);
            }
        }
    }
}

// ---------------- final row softmax over 512 (float2-vectorized; passed r11) ----------------
__global__ __launch_bounds__(256) void softmax512(const float* __restrict__ logits,
                                                  float* __restrict__ out) {
    const int b    = blockIdx.x;
    const int tid  = threadIdx.x;
    const int lane = tid & 63;
    const int w    = tid >> 6;
    const float2* row2 = (const float2*)(logits + (size_t)b * ACTD);
    const float2 x = row2[tid];
    float m = fmaxf(x.x, x.y);
#pragma unroll
    for (int off = 32; off; off >>= 1) m = fmaxf(m, __shfl_xor(m, off));
    __shared__ float sm[4], ss[4];
    if (lane == 0) sm[w] = m;
    __syncthreads();
    m = fmaxf(fmaxf(sm[0], sm[1]), fmaxf(sm[2], sm[3]));
    const float e0 = expf(x.x - m), e1 = expf(x.y - m);
    float t = e0 + e1;
#pragma unroll
    for (int off = 32; off; off >>= 1) t += __shfl_xor(t, off);
    if (lane == 0) ss[w] = t;
    __syncthreads();
    const float inv = 1.f / (ss[0] + ss[1] + ss[2] + ss[3]);
    float2 o; o.x = e0 * inv; o.y = e1 * inv;
    ((float2*)(out + (size_t)b * ACTD))[tid] = o;
}

// ---------------- launch ----------------
extern "C" void kernel_launch(void* const* d_in, const int* in_sizes, int n_in,
                              void* d_out, int out_size, void* d_ws, size_t ws_size,
                              hipStream_t stream) {
    const float* state   = (const float*)d_in[0];
    const float* now_emb = (const float*)d_in[1];
    const float* neigh   = (const float*)d_in[2];
    // d_in[3] = seg_ids: fixed repeat(arange(B), DEG) -> segment b owns rows 32b..32b+31
    const float* attn_w  = (const float*)d_in[4];
    const float* attn_b  = (const float*)d_in[5];
    const float* aw_w    = (const float*)d_in[6];
    const float* aw_b    = (const float*)d_in[7];
    const float* w1      = (const float*)d_in[8];
    const float* b1      = (const float*)d_in[9];
    const float* w2      = (const float*)d_in[10];
    const float* b2      = (const float*)d_in[11];
    const float* w3      = (const float*)d_in[12];
    const float* b3      = (const float*)d_in[13];
    float* out = (float*)d_out;

    char* ws = (char*)d_ws;
    float*          vnow = (float*)(ws + OFF_VNOW);
    float*          vnb  = (float*)(ws + OFF_VNB);
    float*          cnst = (float*)(ws + OFF_CNST);
    __hip_bfloat16* w1T  = (__hip_bfloat16*)(ws + OFF_W1T);
    __hip_bfloat16* w2T  = (__hip_bfloat16*)(ws + OFF_W2T);
    __hip_bfloat16* w3T  = (__hip_bfloat16*)(ws + OFF_W3T);
    __hip_bfloat16* X1   = (__hip_bfloat16*)(ws + OFF_X1);
    __hip_bfloat16* X2   = (__hip_bfloat16*)(ws + OFF_X2);
    __hip_bfloat16* X3   = (__hip_bfloat16*)(ws + OFF_X3);
    float*          lgts = (float*)(ws + OFF_LOG);

    prep_all<<<1409, 256, 0, stream>>>(attn_w, attn_b, aw_w, aw_b, w1, w2, w3,
                                       vnow, vnb, cnst, w1T, w2T, w3T);
    attn_fused<<<B_SEG, 256, 0, stream>>>(state, now_emb, neigh, vnow, vnb, cnst, X1);
    gemm_db<1, 0, 2><<<512,  256, 0, stream>>>(X1, w1T, b1, (void*)X2, 512, 768);
    gemm_db<1, 0, 3><<<1024, 256, 0, stream>>>(X2, w2T, b2, (void*)X3, 1024, 512);
    gemm_db<0, 1, 2><<<512,  256, 0, stream>>>(X3, w3T, b3, (void*)lgts, 512, 1024);
    softmax512<<<B_SEG, 256, 0, stream>>>(lgts, out);
}

// Round 13
// 133.666 us; speedup vs baseline: 1.2338x; 1.2221x over previous
//
#include <hip/hip_runtime.h>
#include <hip/hip_bf16.h>

#define B_SEG  8192
#define DEG    32
#define D_DIM  256
#define TWO_D  512
#define ACTD   512
#define SLOPE  0.2f

typedef __attribute__((ext_vector_type(8))) short bf16x8;   // 8 bf16 (4 VGPRs)
typedef __attribute__((ext_vector_type(4))) float f32x4;

// ---------------- workspace layout (bytes) ----------------
#define OFF_VNOW  ((size_t)0)
#define OFF_VNB   ((size_t)1024)
#define OFF_CNST  ((size_t)2048)
#define OFF_W1T   ((size_t)4096)                               // 512x768 bf16
#define OFF_W2T   (OFF_W1T + (size_t)768*512*2)                // 1024x512 bf16
#define OFF_W3T   (OFF_W2T + (size_t)512*1024*2)               // 512x1024 bf16
#define OFF_X1    (OFF_W3T + (size_t)1024*512*2)               // 8192x768 bf16
#define OFF_X2    (OFF_X1 + (size_t)B_SEG*768*2)               // 8192x512 bf16
#define OFF_X3    (OFF_X2 + (size_t)B_SEG*512*2)               // 8192x1024 bf16
#define OFF_LOG   (OFF_X3 + (size_t)B_SEG*1024*2)              // 8192x512 f32

// ---------------- direct global->LDS (16B/lane) ----------------
typedef const unsigned int __attribute__((address_space(1)))* gas_ptr;
typedef unsigned int __attribute__((address_space(3)))* las_ptr;

__device__ __forceinline__ void gload_lds16(const void* g, void* l) {
    __builtin_amdgcn_global_load_lds((gas_ptr)g, (las_ptr)l, 16, 0, 0);
}

// ---------------- merged prep: vectors (block 0) + 3 weight transposes (round-6 exact) ----------------
__global__ __launch_bounds__(256) void prep_all(
        const float* __restrict__ attn_w, const float* __restrict__ attn_b,
        const float* __restrict__ aw_w, const float* __restrict__ aw_b,
        const float* __restrict__ w1, const float* __restrict__ w2, const float* __restrict__ w3,
        float* __restrict__ vnow, float* __restrict__ vnb, float* __restrict__ cnst,
        __hip_bfloat16* __restrict__ w1T, __hip_bfloat16* __restrict__ w2T,
        __hip_bfloat16* __restrict__ w3T) {
    int bid = blockIdx.x;
    if (bid == 0) {
        const int d = threadIdx.x;   // 0..255
        float s0 = 0.f, s1 = 0.f;
        for (int a = 0; a < 128; ++a) {
            const float w = attn_w[d * 128 + a];
            s0 = fmaf(w, aw_w[a], s0);
            s1 = fmaf(w, aw_w[128 + a], s1);
        }
        vnow[d] = s0;
        vnb[d]  = s1;
        if (d == 0) {
            float c = aw_b[0];
            for (int a = 0; a < 128; ++a) c = fmaf(attn_b[a], aw_w[a] + aw_w[128 + a], c);
            cnst[0] = c;
        }
        return;
    }
    bid -= 1;
    const float* src;
    __hip_bfloat16* dst;
    int K, N;
    if (bid < 384)      { src = w1; dst = w1T; K = 768;  N = 512;  }
    else if (bid < 896) { bid -= 384; src = w2; dst = w2T; K = 512;  N = 1024; }
    else                { bid -= 896; src = w3; dst = w3T; K = 1024; N = 512;  }
    const int tk = K >> 5;
    const int bk = (bid % tk) * 32;
    const int bn = (bid / tk) * 32;

    __shared__ float tile[32][33];
    const int tx = threadIdx.x & 31;
    const int ty = threadIdx.x >> 5;   // 0..7
#pragma unroll
    for (int i = 0; i < 32; i += 8)
        tile[ty + i][tx] = src[(size_t)(bk + ty + i) * N + (bn + tx)];
    __syncthreads();
#pragma unroll
    for (int i = 0; i < 32; i += 8)
        dst[(size_t)(bn + ty + i) * K + (bk + tx)] = __float2bfloat16(tile[tx][ty + i]);
}

// ---------------- fused attention (round-2 verified, untouched) ----------------
__global__ __launch_bounds__(256) void attn_fused(
        const float* __restrict__ state, const float* __restrict__ now_emb,
        const float* __restrict__ neigh, const float* __restrict__ vnow,
        const float* __restrict__ vnb, const float* __restrict__ cnst,
        __hip_bfloat16* __restrict__ X1) {
    const int b    = blockIdx.x;
    const int tid  = threadIdx.x;
    const int lane = tid & 63;
    const int w    = tid >> 6;     // wave 0..3
    const int l4   = lane * 4;

    __shared__ float s_score[DEG];
    __shared__ float s_now;
    __shared__ float s_part[4][D_DIM];   // 4 KB

    const float4 vb = *(const float4*)&vnb[l4];
    float4 nv[8];
#pragma unroll
    for (int i = 0; i < 8; ++i) {
        const int e = w * 8 + i;
        nv[i] = *(const float4*)&neigh[((size_t)b * DEG + e) * D_DIM + l4];
        float p = nv[i].x * vb.x + nv[i].y * vb.y + nv[i].z * vb.z + nv[i].w * vb.w;
#pragma unroll
        for (int off = 32; off; off >>= 1) p += __shfl_xor(p, off);
        if (lane == 0) s_score[e] = p;
    }
    if (w == 0) {
        const float4 va = *(const float4*)&vnow[l4];
        const float4 ne = *(const float4*)&now_emb[(size_t)b * D_DIM + l4];
        float p = ne.x * va.x + ne.y * va.y + ne.z * va.z + ne.w * va.w;
#pragma unroll
        for (int off = 32; off; off >>= 1) p += __shfl_xor(p, off);
        if (lane == 0) s_now = p + cnst[0];
    }
    __syncthreads();

    if (w == 0) {
        float s = (lane < DEG) ? (s_score[lane] + s_now) : -3.4e38f;
        s = (s >= 0.f) ? s : SLOPE * s;
        float m = s;
#pragma unroll
        for (int off = 32; off; off >>= 1) m = fmaxf(m, __shfl_xor(m, off));
        const float e = (lane < DEG) ? expf(s - m) : 0.f;
        float t = e;
#pragma unroll
        for (int off = 32; off; off >>= 1) t += __shfl_xor(t, off);
        if (lane < DEG) s_score[lane] = e / t;          // alpha
    }
    __syncthreads();

    float4 part = {0.f, 0.f, 0.f, 0.f};
#pragma unroll
    for (int i = 0; i < 8; ++i) {
        const float al = s_score[w * 8 + i];
        part.x = fmaf(al, nv[i].x, part.x);
        part.y = fmaf(al, nv[i].y, part.y);
        part.z = fmaf(al, nv[i].z, part.z);
        part.w = fmaf(al, nv[i].w, part.w);
    }
    *(float4*)&s_part[w][l4] = part;
    __syncthreads();

    const float a = s_part[0][tid] + s_part[1][tid] + s_part[2][tid] + s_part[3][tid];

    __hip_bfloat16* xrow = X1 + (size_t)b * 768;
    xrow[512 + tid] = __float2bfloat16(a);
    const float2 st = *(const float2*)&state[(size_t)b * TWO_D + 2 * tid];
    __hip_bfloat162 h;
    h.x = __float2bfloat16(st.x);
    h.y = __float2bfloat16(st.y);
    *(__hip_bfloat162*)&xrow[2 * tid] = h;
}

// ---------------- bf16 MFMA GEMM v3 (round-6 exact): 64x128, BK=64, counted-vmcnt dbuf, swizzled ----------------
template <int RELU, int OUTF32, int LN_N>
__global__ __launch_bounds__(256) void gemm_db(
        const __hip_bfloat16* __restrict__ A, const __hip_bfloat16* __restrict__ BT,
        const float* __restrict__ bias, void* __restrict__ Cout, int N, int K) {
    __shared__ __hip_bfloat16 sA[2][64 * 64];    // 8 KB per buf
    __shared__ __hip_bfloat16 sB[2][128 * 64];   // 16 KB per buf  (48 KB total)

    const int tid  = threadIdx.x;
    const int lane = tid & 63;
    const int wv   = tid >> 6;
    const int wr   = wv >> 1;
    const int wc   = wv & 1;

    // XCD swizzle (m157; nwg % 8 == 0 for all three launches)
    const int cpx = (int)gridDim.x >> 3;
    const int swz = ((int)blockIdx.x & 7) * cpx + ((int)blockIdx.x >> 3);
    const size_t mBase = (size_t)(swz >> LN_N) * 64;
    const size_t nBase = (size_t)(swz & ((1 << LN_N) - 1)) * 128;
    const size_t Kb = (size_t)K * 2;

    f32x4 acc[2][4];
#pragma unroll
    for (int r = 0; r < 2; ++r)
#pragma unroll
        for (int c = 0; c < 4; ++c) acc[r][c] = (f32x4){0.f, 0.f, 0.f, 0.f};

    const int srow  = tid >> 3;                          // 0..31
    const int kbLog = ((tid & 7) ^ (srow & 7)) << 4;     // pre-swizzled source k-byte (rule 21)
    const char* gA = (const char*)A  + (mBase + srow) * Kb + kbLog;
    const char* gB = (const char*)BT + (nBase + srow) * Kb + kbLog;
    char* lA = (char*)&sA[0][0] + tid * 16;
    char* lB = (char*)&sB[0][0] + tid * 16;

    const int fr  = lane & 15;
    const int fkb = (lane >> 4) * 16;
    const char* sAb = (const char*)&sA[0][0];
    const char* sBb = (const char*)&sB[0][0];

    const int nk = K >> 6;

#define STAGE(T, BUF) do {                                                         \
        const size_t kOff = (size_t)(T) * 128;                                     \
        gload_lds16(gA + kOff,           lA + (BUF) * 8192);                       \
        gload_lds16(gA + kOff + 32 * Kb, lA + (BUF) * 8192 + 4096);                \
        gload_lds16(gB + kOff,           lB + (BUF) * 16384);                      \
        gload_lds16(gB + kOff + 32 * Kb, lB + (BUF) * 16384 + 4096);               \
        gload_lds16(gB + kOff + 64 * Kb, lB + (BUF) * 16384 + 8192);               \
        gload_lds16(gB + kOff + 96 * Kb, lB + (BUF) * 16384 + 12288);              \
    } while (0)

#define SWZ(ROW, KB) ((ROW) * 128 + ((KB) ^ (((ROW) & 7) << 4)))

    STAGE(0, 0);

    int cur = 0;
    for (int t = 0; t < nk; ++t) {
        if (t + 1 < nk) {
            STAGE(t + 1, cur ^ 1);                          // issue next tile's 6 loads
            asm volatile("s_waitcnt vmcnt(6)" ::: "memory"); // drain only tile t's loads
        } else {
            asm volatile("s_waitcnt vmcnt(0)" ::: "memory"); // last tile: full drain
        }
        __builtin_amdgcn_s_barrier();        // tile t staged + visible to all waves
        __builtin_amdgcn_sched_barrier(0);   // no ds_read hoists above the barrier

        const char* bufA = sAb + cur * 8192;
        const char* bufB = sBb + cur * 16384;
#pragma unroll
        for (int ks = 0; ks < 2; ++ks) {
            bf16x8 aF[2], bF[4];
#pragma unroll
            for (int r = 0; r < 2; ++r) {
                const int row = wr * 32 + r * 16 + fr;
                aF[r] = *(const bf16x8*)(bufA + SWZ(row, ks * 64 + fkb));
            }
#pragma unroll
            for (int c = 0; c < 4; ++c) {
                const int row = wc * 64 + c * 16 + fr;
                bF[c] = *(const bf16x8*)(bufB + SWZ(row, ks * 64 + fkb));
            }
#pragma unroll
            for (int r = 0; r < 2; ++r)
#pragma unroll
                for (int c = 0; c < 4; ++c)
                    acc[r][c] = __builtin_amdgcn_mfma_f32_16x16x32_bf16(aF[r], bF[c], acc[r][c], 0, 0, 0);
        }
        __builtin_amdgcn_sched_barrier(0);   // no read sinks below the barrier
        __builtin_amdgcn_s_barrier();        // all waves done reading buf[cur]
        cur ^= 1;
    }
#undef STAGE
#undef SWZ

    // epilogue: C/D layout col = lane&15, row = (lane>>4)*4 + q  [m89-verified]
    const int fq = lane >> 4;
#pragma unroll
    for (int r = 0; r < 2; ++r) {
#pragma unroll
        for (int c = 0; c < 4; ++c) {
            const size_t col = nBase + wc * 64 + c * 16 + fr;
            const float bcol = bias[col];
#pragma unroll
            for (int q = 0; q < 4; ++q) {
                const size_t row = mBase + wr * 32 + r * 16 + fq * 4 + q;
                float v = acc[r][c][q] + bcol;
                if (RELU) v = fmaxf(v, 0.f);
                if (OUTF32) ((float*)Cout)[row * N + col] = v;
                else ((__hip_bfloat16*)Cout)[row * N + col] = __float2bfloat16(v);
            }
        }
    }
}

// ---------------- final row softmax over 512 (round-6 exact) ----------------
__global__ __launch_bounds__(256) void softmax512(const float* __restrict__ logits,
                                                  float* __restrict__ out) {
    const int b    = blockIdx.x;
    const int tid  = threadIdx.x;
    const int lane = tid & 63;
    const int w    = tid >> 6;
    const float* row = logits + (size_t)b * ACTD;
    const float x0 = row[tid], x1 = row[tid + 256];
    float m = fmaxf(x0, x1);
#pragma unroll
    for (int off = 32; off; off >>= 1) m = fmaxf(m, __shfl_xor(m, off));
    __shared__ float sm[4], ss[4];
    if (lane == 0) sm[w] = m;
    __syncthreads();
    m = fmaxf(fmaxf(sm[0], sm[1]), fmaxf(sm[2], sm[3]));
    const float e0 = expf(x0 - m), e1 = expf(x1 - m);
    float t = e0 + e1;
#pragma unroll
    for (int off = 32; off; off >>= 1) t += __shfl_xor(t, off);
    if (lane == 0) ss[w] = t;
    __syncthreads();
    const float inv = 1.f / (ss[0] + ss[1] + ss[2] + ss[3]);
    out[(size_t)b * ACTD + tid]       = e0 * inv;
    out[(size_t)b * ACTD + tid + 256] = e1 * inv;
}

// ---------------- launch ----------------
extern "C" void kernel_launch(void* const* d_in, const int* in_sizes, int n_in,
                              void* d_out, int out_size, void* d_ws, size_t ws_size,
                              hipStream_t stream) {
    const float* state   = (const float*)d_in[0];
    const float* now_emb = (const float*)d_in[1];
    const float* neigh   = (const float*)d_in[2];
    // d_in[3] = seg_ids: fixed repeat(arange(B), DEG) -> segment b owns rows 32b..32b+31
    const float* attn_w  = (const float*)d_in[4];
    const float* attn_b  = (const float*)d_in[5];
    const float* aw_w    = (const float*)d_in[6];
    const float* aw_b    = (const float*)d_in[7];
    const float* w1      = (const float*)d_in[8];
    const float* b1      = (const float*)d_in[9];
    const float* w2      = (const float*)d_in[10];
    const float* b2      = (const float*)d_in[11];
    const float* w3      = (const float*)d_in[12];
    const float* b3      = (const float*)d_in[13];
    float* out = (float*)d_out;

    char* ws = (char*)d_ws;
    float*          vnow = (float*)(ws + OFF_VNOW);
    float*          vnb  = (float*)(ws + OFF_VNB);
    float*          cnst = (float*)(ws + OFF_CNST);
    __hip_bfloat16* w1T  = (__hip_bfloat16*)(ws + OFF_W1T);
    __hip_bfloat16* w2T  = (__hip_bfloat16*)(ws + OFF_W2T);
    __hip_bfloat16* w3T  = (__hip_bfloat16*)(ws + OFF_W3T);
    __hip_bfloat16* X1   = (__hip_bfloat16*)(ws + OFF_X1);
    __hip_bfloat16* X2   = (__hip_bfloat16*)(ws + OFF_X2);
    __hip_bfloat16* X3   = (__hip_bfloat16*)(ws + OFF_X3);
    float*          lgts = (float*)(ws + OFF_LOG);

    prep_all<<<1409, 256, 0, stream>>>(attn_w, attn_b, aw_w, aw_b, w1, w2, w3,
                                       vnow, vnb, cnst, w1T, w2T, w3T);
    attn_fused<<<B_SEG, 256, 0, stream>>>(state, now_emb, neigh, vnow, vnb, cnst, X1);
    gemm_db<1, 0, 2><<<512,  256, 0, stream>>>(X1, w1T, b1, (void*)X2, 512, 768);
    gemm_db<1, 0, 3><<<1024, 256, 0, stream>>>(X2, w2T, b2, (void*)X3, 1024, 512);
    gemm_db<0, 1, 2><<<512,  256, 0, stream>>>(X3, w3T, b3, (void*)lgts, 512, 1024);
    softmax512<<<B_SEG, 256, 0, stream>>>(lgts, out);
}

// Round 14
// 131.051 us; speedup vs baseline: 1.2584x; 1.0200x over previous
//
#include <hip/hip_runtime.h>
#include <hip/hip_bf16.h>

#define B_SEG  8192
#define DEG    32
#define D_DIM  256
#define TWO_D  512
#define ACTD   512
#define SLOPE  0.2f

typedef __attribute__((ext_vector_type(8))) short bf16x8;   // 8 bf16 (4 VGPRs)
typedef __attribute__((ext_vector_type(4))) float f32x4;

// ---------------- workspace layout (bytes) ----------------
#define OFF_VNOW  ((size_t)0)
#define OFF_VNB   ((size_t)1024)
#define OFF_CNST  ((size_t)2048)
#define OFF_W1T   ((size_t)4096)                               // 512x768 bf16
#define OFF_W2T   (OFF_W1T + (size_t)768*512*2)                // 1024x512 bf16
#define OFF_W3T   (OFF_W2T + (size_t)512*1024*2)               // 512x1024 bf16
#define OFF_X1    (OFF_W3T + (size_t)1024*512*2)               // 8192x768 bf16
#define OFF_X2    (OFF_X1 + (size_t)B_SEG*768*2)               // 8192x512 bf16
#define OFF_X3    (OFF_X2 + (size_t)B_SEG*512*2)               // 8192x1024 bf16
#define OFF_LOG   (OFF_X3 + (size_t)B_SEG*1024*2)              // 8192x512 f32

// ---------------- direct global->LDS (16B/lane) ----------------
typedef const unsigned int __attribute__((address_space(1)))* gas_ptr;
typedef unsigned int __attribute__((address_space(3)))* las_ptr;

__device__ __forceinline__ void gload_lds16(const void* g, void* l) {
    __builtin_amdgcn_global_load_lds((gas_ptr)g, (las_ptr)l, 16, 0, 0);
}

// ---------------- merged prep: vectors (block 0, SCALAR r13-verified) + 3 transposes ----------------
// NOTE: the "coalesced" block-0 rewrite (r8-r12) cost ~30 us: unroll-2 capped MLP at 2
// in-flight row loads and the per-iteration shfl chain serialized behind each load,
// delaying the dependent attn launch. The scalar per-thread loop pipelines 128
// independent loads per thread and is fast. Keep scalar.
__global__ __launch_bounds__(256) void prep_all(
        const float* __restrict__ attn_w, const float* __restrict__ attn_b,
        const float* __restrict__ aw_w, const float* __restrict__ aw_b,
        const float* __restrict__ w1, const float* __restrict__ w2, const float* __restrict__ w3,
        float* __restrict__ vnow, float* __restrict__ vnb, float* __restrict__ cnst,
        __hip_bfloat16* __restrict__ w1T, __hip_bfloat16* __restrict__ w2T,
        __hip_bfloat16* __restrict__ w3T) {
    int bid = blockIdx.x;
    if (bid == 0) {
        const int d = threadIdx.x;   // 0..255
        float s0 = 0.f, s1 = 0.f;
        for (int a = 0; a < 128; ++a) {
            const float w = attn_w[d * 128 + a];
            s0 = fmaf(w, aw_w[a], s0);
            s1 = fmaf(w, aw_w[128 + a], s1);
        }
        vnow[d] = s0;
        vnb[d]  = s1;
        if (d == 0) {
            float c = aw_b[0];
            for (int a = 0; a < 128; ++a) c = fmaf(attn_b[a], aw_w[a] + aw_w[128 + a], c);
            cnst[0] = c;
        }
        return;
    }
    bid -= 1;
    const float* src;
    __hip_bfloat16* dst;
    int K, N;
    if (bid < 384)      { src = w1; dst = w1T; K = 768;  N = 512;  }
    else if (bid < 896) { bid -= 384; src = w2; dst = w2T; K = 512;  N = 1024; }
    else                { bid -= 896; src = w3; dst = w3T; K = 1024; N = 512;  }
    const int tk = K >> 5;
    const int bk = (bid % tk) * 32;
    const int bn = (bid / tk) * 32;

    __shared__ float tile[32][33];
    const int tx = threadIdx.x & 31;
    const int ty = threadIdx.x >> 5;   // 0..7
#pragma unroll
    for (int i = 0; i < 32; i += 8)
        tile[ty + i][tx] = src[(size_t)(bk + ty + i) * N + (bn + tx)];
    __syncthreads();
#pragma unroll
    for (int i = 0; i < 32; i += 8)
        dst[(size_t)(bn + ty + i) * K + (bk + tx)] = __float2bfloat16(tile[tx][ty + i]);
}

// ---------------- fused attention (round-2 verified, untouched) ----------------
__global__ __launch_bounds__(256) void attn_fused(
        const float* __restrict__ state, const float* __restrict__ now_emb,
        const float* __restrict__ neigh, const float* __restrict__ vnow,
        const float* __restrict__ vnb, const float* __restrict__ cnst,
        __hip_bfloat16* __restrict__ X1) {
    const int b    = blockIdx.x;
    const int tid  = threadIdx.x;
    const int lane = tid & 63;
    const int w    = tid >> 6;     // wave 0..3
    const int l4   = lane * 4;

    __shared__ float s_score[DEG];
    __shared__ float s_now;
    __shared__ float s_part[4][D_DIM];   // 4 KB

    const float4 vb = *(const float4*)&vnb[l4];
    float4 nv[8];
#pragma unroll
    for (int i = 0; i < 8; ++i) {
        const int e = w * 8 + i;
        nv[i] = *(const float4*)&neigh[((size_t)b * DEG + e) * D_DIM + l4];
        float p = nv[i].x * vb.x + nv[i].y * vb.y + nv[i].z * vb.z + nv[i].w * vb.w;
#pragma unroll
        for (int off = 32; off; off >>= 1) p += __shfl_xor(p, off);
        if (lane == 0) s_score[e] = p;
    }
    if (w == 0) {
        const float4 va = *(const float4*)&vnow[l4];
        const float4 ne = *(const float4*)&now_emb[(size_t)b * D_DIM + l4];
        float p = ne.x * va.x + ne.y * va.y + ne.z * va.z + ne.w * va.w;
#pragma unroll
        for (int off = 32; off; off >>= 1) p += __shfl_xor(p, off);
        if (lane == 0) s_now = p + cnst[0];
    }
    __syncthreads();

    if (w == 0) {
        float s = (lane < DEG) ? (s_score[lane] + s_now) : -3.4e38f;
        s = (s >= 0.f) ? s : SLOPE * s;
        float m = s;
#pragma unroll
        for (int off = 32; off; off >>= 1) m = fmaxf(m, __shfl_xor(m, off));
        const float e = (lane < DEG) ? expf(s - m) : 0.f;
        float t = e;
#pragma unroll
        for (int off = 32; off; off >>= 1) t += __shfl_xor(t, off);
        if (lane < DEG) s_score[lane] = e / t;          // alpha
    }
    __syncthreads();

    float4 part = {0.f, 0.f, 0.f, 0.f};
#pragma unroll
    for (int i = 0; i < 8; ++i) {
        const float al = s_score[w * 8 + i];
        part.x = fmaf(al, nv[i].x, part.x);
        part.y = fmaf(al, nv[i].y, part.y);
        part.z = fmaf(al, nv[i].z, part.z);
        part.w = fmaf(al, nv[i].w, part.w);
    }
    *(float4*)&s_part[w][l4] = part;
    __syncthreads();

    const float a = s_part[0][tid] + s_part[1][tid] + s_part[2][tid] + s_part[3][tid];

    __hip_bfloat16* xrow = X1 + (size_t)b * 768;
    xrow[512 + tid] = __float2bfloat16(a);
    const float2 st = *(const float2*)&state[(size_t)b * TWO_D + 2 * tid];
    __hip_bfloat162 h;
    h.x = __float2bfloat16(st.x);
    h.y = __float2bfloat16(st.y);
    *(__hip_bfloat162*)&xrow[2 * tid] = h;
}

// ---------------- bf16 MFMA GEMM v5 (r9 verbatim, deconfounded net winner): 64x64, BK=64,
// 2-buffer counted-vmcnt, swizzled LDS. LDS 32 KB -> 4-5 blocks/CU; cross-block overlap
// (m114) hides staging latency better than 64x128's per-block compute.
template <int RELU, int OUTF32, int LN_N>
__global__ __launch_bounds__(256) void gemm_db(
        const __hip_bfloat16* __restrict__ A, const __hip_bfloat16* __restrict__ BT,
        const float* __restrict__ bias, void* __restrict__ Cout, int N, int K) {
    __shared__ __hip_bfloat16 sA[2][64 * 64];    // 8 KB per buf
    __shared__ __hip_bfloat16 sB[2][64 * 64];    // 8 KB per buf  (32 KB total)

    const int tid  = threadIdx.x;
    const int lane = tid & 63;
    const int wv   = tid >> 6;
    const int wr   = wv >> 1;    // wave row 0..1
    const int wc   = wv & 1;     // wave col 0..1

    // XCD swizzle (m157; nwg % 8 == 0 for all three launches)
    const int cpx = (int)gridDim.x >> 3;
    const int swz = ((int)blockIdx.x & 7) * cpx + ((int)blockIdx.x >> 3);
    const size_t mBase = (size_t)(swz >> LN_N) * 64;
    const size_t nBase = (size_t)(swz & ((1 << LN_N) - 1)) * 64;
    const size_t Kb = (size_t)K * 2;

    f32x4 acc[2][2];
#pragma unroll
    for (int r = 0; r < 2; ++r)
#pragma unroll
        for (int c = 0; c < 2; ++c) acc[r][c] = (f32x4){0.f, 0.f, 0.f, 0.f};

    const int srow  = tid >> 3;                          // 0..31
    const int kbLog = ((tid & 7) ^ (srow & 7)) << 4;     // pre-swizzled source k-byte (rule 21)
    const char* gA = (const char*)A  + (mBase + srow) * Kb + kbLog;
    const char* gB = (const char*)BT + (nBase + srow) * Kb + kbLog;
    char* lA = (char*)&sA[0][0] + tid * 16;
    char* lB = (char*)&sB[0][0] + tid * 16;

    const int fr  = lane & 15;
    const int fkb = (lane >> 4) * 16;
    const char* sAb = (const char*)&sA[0][0];
    const char* sBb = (const char*)&sB[0][0];

    const int nk = K >> 6;   // 64-wide k-chunks

#define STAGE(T, BUF) do {                                                         \
        const size_t kOff = (size_t)(T) * 128;                                     \
        gload_lds16(gA + kOff,           lA + (size_t)(BUF) * 8192);               \
        gload_lds16(gA + kOff + 32 * Kb, lA + (size_t)(BUF) * 8192 + 4096);        \
        gload_lds16(gB + kOff,           lB + (size_t)(BUF) * 8192);               \
        gload_lds16(gB + kOff + 32 * Kb, lB + (size_t)(BUF) * 8192 + 4096);        \
    } while (0)

#define SWZ(ROW, KB) ((ROW) * 128 + ((KB) ^ (((ROW) & 7) << 4)))

    STAGE(0, 0);

    int cur = 0;
    for (int t = 0; t < nk; ++t) {
        if (t + 1 < nk) {
            STAGE(t + 1, cur ^ 1);                          // issue next tile's 4 loads
            asm volatile("s_waitcnt vmcnt(4)" ::: "memory"); // drain only tile t's loads
        } else {
            asm volatile("s_waitcnt vmcnt(0)" ::: "memory"); // last tile: full drain
        }
        __builtin_amdgcn_s_barrier();        // tile t staged + visible to all waves
        __builtin_amdgcn_sched_barrier(0);   // no ds_read hoists above the barrier

        const char* bufA = sAb + (size_t)cur * 8192;
        const char* bufB = sBb + (size_t)cur * 8192;
#pragma unroll
        for (int ks = 0; ks < 2; ++ks) {
            bf16x8 aF[2], bF[2];
#pragma unroll
            for (int r = 0; r < 2; ++r) {
                const int row = wr * 32 + r * 16 + fr;
                aF[r] = *(const bf16x8*)(bufA + SWZ(row, ks * 64 + fkb));
            }
#pragma unroll
            for (int c = 0; c < 2; ++c) {
                const int row = wc * 32 + c * 16 + fr;
                bF[c] = *(const bf16x8*)(bufB + SWZ(row, ks * 64 + fkb));
            }
#pragma unroll
            for (int r = 0; r < 2; ++r)
#pragma unroll
                for (int c = 0; c < 2; ++c)
                    acc[r][c] = __builtin_amdgcn_mfma_f32_16x16x32_bf16(aF[r], bF[c], acc[r][c], 0, 0, 0);
        }
        __builtin_amdgcn_sched_barrier(0);   // no read sinks below the barrier
        __builtin_amdgcn_s_barrier();        // all waves done reading buf[cur]
        cur ^= 1;
    }
#undef STAGE
#undef SWZ

    // epilogue: C/D layout col = lane&15, row = (lane>>4)*4 + q  [m89-verified]
    const int fq = lane >> 4;
#pragma unroll
    for (int r = 0; r < 2; ++r) {
#pragma unroll
        for (int c = 0; c < 2; ++c) {
            const size_t col = nBase + wc * 32 + c * 16 + fr;
            const float bcol = bias[col];
#pragma unroll
            for (int q = 0; q < 4; ++q) {
                const size_t row = mBase + wr * 32 + r * 16 + fq * 4 + q;
                float v = acc[r][c][q] + bcol;
                if (RELU) v = fmaxf(v, 0.f);
                if (OUTF32) ((float*)Cout)[row * N + col] = v;
                else ((__hip_bfloat16*)Cout)[row * N + col] = __float2bfloat16(v);
            }
        }
    }
}

// ---------------- final row softmax over 512 (r13 exact) ----------------
__global__ __launch_bounds__(256) void softmax512(const float* __restrict__ logits,
                                                  float* __restrict__ out) {
    const int b    = blockIdx.x;
    const int tid  = threadIdx.x;
    const int lane = tid & 63;
    const int w    = tid >> 6;
    const float* row = logits + (size_t)b * ACTD;
    const float x0 = row[tid], x1 = row[tid + 256];
    float m = fmaxf(x0, x1);
#pragma unroll
    for (int off = 32; off; off >>= 1) m = fmaxf(m, __shfl_xor(m, off));
    __shared__ float sm[4], ss[4];
    if (lane == 0) sm[w] = m;
    __syncthreads();
    m = fmaxf(fmaxf(sm[0], sm[1]), fmaxf(sm[2], sm[3]));
    const float e0 = expf(x0 - m), e1 = expf(x1 - m);
    float t = e0 + e1;
#pragma unroll
    for (int off = 32; off; off >>= 1) t += __shfl_xor(t, off);
    if (lane == 0) ss[w] = t;
    __syncthreads();
    const float inv = 1.f / (ss[0] + ss[1] + ss[2] + ss[3]);
    out[(size_t)b * ACTD + tid]       = e0 * inv;
    out[(size_t)b * ACTD + tid + 256] = e1 * inv;
}

// ---------------- launch ----------------
extern "C" void kernel_launch(void* const* d_in, const int* in_sizes, int n_in,
                              void* d_out, int out_size, void* d_ws, size_t ws_size,
                              hipStream_t stream) {
    const float* state   = (const float*)d_in[0];
    const float* now_emb = (const float*)d_in[1];
    const float* neigh   = (const float*)d_in[2];
    // d_in[3] = seg_ids: fixed repeat(arange(B), DEG) -> segment b owns rows 32b..32b+31
    const float* attn_w  = (const float*)d_in[4];
    const float* attn_b  = (const float*)d_in[5];
    const float* aw_w    = (const float*)d_in[6];
    const float* aw_b    = (const float*)d_in[7];
    const float* w1      = (const float*)d_in[8];
    const float* b1      = (const float*)d_in[9];
    const float* w2      = (const float*)d_in[10];
    const float* b2      = (const float*)d_in[11];
    const float* w3      = (const float*)d_in[12];
    const float* b3      = (const float*)d_in[13];
    float* out = (float*)d_out;

    char* ws = (char*)d_ws;
    float*          vnow = (float*)(ws + OFF_VNOW);
    float*          vnb  = (float*)(ws + OFF_VNB);
    float*          cnst = (float*)(ws + OFF_CNST);
    __hip_bfloat16* w1T  = (__hip_bfloat16*)(ws + OFF_W1T);
    __hip_bfloat16* w2T  = (__hip_bfloat16*)(ws + OFF_W2T);
    __hip_bfloat16* w3T  = (__hip_bfloat16*)(ws + OFF_W3T);
    __hip_bfloat16* X1   = (__hip_bfloat16*)(ws + OFF_X1);
    __hip_bfloat16* X2   = (__hip_bfloat16*)(ws + OFF_X2);
    __hip_bfloat16* X3   = (__hip_bfloat16*)(ws + OFF_X3);
    float*          lgts = (float*)(ws + OFF_LOG);

    prep_all<<<1409, 256, 0, stream>>>(attn_w, attn_b, aw_w, aw_b, w1, w2, w3,
                                       vnow, vnb, cnst, w1T, w2T, w3T);
    attn_fused<<<B_SEG, 256, 0, stream>>>(state, now_emb, neigh, vnow, vnb, cnst, X1);
    gemm_db<1, 0, 3><<<1024, 256, 0, stream>>>(X1, w1T, b1, (void*)X2, 512, 768);
    gemm_db<1, 0, 4><<<2048, 256, 0, stream>>>(X2, w2T, b2, (void*)X3, 1024, 512);
    gemm_db<0, 1, 3><<<1024, 256, 0, stream>>>(X3, w3T, b3, (void*)lgts, 512, 1024);
    softmax512<<<B_SEG, 256, 0, stream>>>(lgts, out);
}